// Round 8
// baseline (106.650 us; speedup 1.0000x reference)
//
#include <hip/hip_runtime.h>

// RelativePositionalEncoding2D: out[b,i,j,e] = W[e, pos] + bias[e]
//   pos = clip(idxs[b,j] - idxs[b,i], -32, 32) + 32
// Shapes: B=1, S=1024, E=128, N=65. Output fp32 (1,S,S,E) = 512 MiB -> pure
// HBM-write-bound (floor ~80us at ~6.7 TB/s measured fill BW).
//
// R7 -> R8: eliminate the LDS table entirely (two-kernel design).
//  k1: precompute table[p][e] = W[e,p]+b[e] (33 KB) into d_ws.
//  k2: main kernel reads table + idxs straight from global (L1-resident:
//      33 KB table + 4 KB idxs, same addresses for every wave on a CU).
//      -> zero LDS, zero barrier, zero per-block prologue; 8 blocks/CU
//      (vs 4 with LDS), 2048 blocks fully resident in ONE generation.
// R7's branch experiment exonerated LDS-read latency; this attacks the two
// remaining structural gaps vs the fill kernel: per-block prologue x2
// generations, and store-queue depth via occupancy.

#define MAXGAP 32
#define NIDX   65     // 2*MAXGAP+1
#define EDIM   128
#define E4     32     // EDIM/4 float4 per output row
#define PADE   132    // padded LDS row stride (fallback kernel only)
#define CHUNKS 2      // half-rows per i

typedef float f32x4 __attribute__((ext_vector_type(4)));

// ---- k1: build table in workspace: tbl[p*EDIM + e] = W[e*NIDX+p] + bias[e]
__global__ __launch_bounds__(256) void build_table_kernel(
    const float* __restrict__ W, const float* __restrict__ bias,
    float* __restrict__ tbl)
{
    int t = blockIdx.x * 256 + threadIdx.x;
    if (t < NIDX * EDIM) {
        float w = W[t];              // coalesced: t = e*NIDX + p
        int e = t / NIDX;
        int p = t - e * NIDX;
        tbl[p * EDIM + e] = w + bias[e];
    }
}

// ---- k2: pure streaming store kernel, no LDS, no barrier
__global__ __launch_bounds__(256, 8) void relpos2d_stream_kernel(
    const int* __restrict__ idxs,
    const f32x4* __restrict__ tbl4,    // (NIDX, E4)
    f32x4* __restrict__ out,           // (S*S, E4)
    int S, int halfS)
{
    const int i     = blockIdx.x >> 1;        // CHUNKS == 2
    const int chunk = blockIdx.x & (CHUNKS - 1);
    const int jbase = chunk * halfS;

    const int lane4 = threadIdx.x & 31;
    const int jsub  = threadIdx.x >> 5;       // 0..7
    const int idx_i = idxs[i];

    const int* __restrict__ jptr = idxs + jbase;
    f32x4* __restrict__ orow = out + (size_t)i * S * E4 + (size_t)jbase * E4;

    #pragma unroll 4
    for (int jj = 0; jj < halfS; jj += 8) {
        int j = jj + jsub;
        int d = jptr[j] - idx_i;              // L1-hit broadcast load
        d = d < -MAXGAP ? -MAXGAP : (d > MAXGAP ? MAXGAP : d);
        int p = d + MAXGAP;

        f32x4 v = tbl4[p * E4 + lane4];       // L1-hit (33 KB resident)
        orow[(size_t)j * E4 + lane4] = v;
    }
}

// ---- fallback (R6 best-known single-kernel) if ws_size is too small
__global__ __launch_bounds__(256) void relpos2d_lds_kernel(
    const int* __restrict__ idxs,
    const float* __restrict__ W,
    const float* __restrict__ bias,
    f32x4* __restrict__ out,
    int S, int halfS)
{
    __shared__ float table[NIDX * PADE];
    __shared__ int   jidx[512];

    for (int t = threadIdx.x; t < NIDX * EDIM; t += 256) {
        float w = W[t];
        int e = t / NIDX;
        int p = t - e * NIDX;
        table[p * PADE + e] = w + bias[e];
    }

    const int i     = blockIdx.x >> 1;
    const int chunk = blockIdx.x & (CHUNKS - 1);
    const int jbase = chunk * halfS;

    for (int t = threadIdx.x; t < halfS; t += 256)
        jidx[t] = idxs[jbase + t];

    __syncthreads();

    const int lane4 = threadIdx.x & 31;
    const int jsub  = threadIdx.x >> 5;
    const int idx_i = idxs[i];

    f32x4* __restrict__ orow = out + (size_t)i * S * E4 + (size_t)jbase * E4;

    #pragma unroll 4
    for (int jj = 0; jj < halfS; jj += 8) {
        int j = jj + jsub;
        int d = jidx[j] - idx_i;
        d = d < -MAXGAP ? -MAXGAP : (d > MAXGAP ? MAXGAP : d);
        int p = d + MAXGAP;

        f32x4 v = reinterpret_cast<const f32x4*>(&table[p * PADE])[lane4];
        orow[(size_t)j * E4 + lane4] = v;
    }
}

extern "C" void kernel_launch(void* const* d_in, const int* in_sizes, int n_in,
                              void* d_out, int out_size, void* d_ws, size_t ws_size,
                              hipStream_t stream) {
    const int*   idxs = (const int*)  d_in[0];   // (B*S,) int32, B=1
    const float* W    = (const float*)d_in[1];   // (E, N) fp32
    const float* bias = (const float*)d_in[2];   // (E,)  fp32

    f32x4* out = (f32x4*)d_out;

    const int S     = in_sizes[0];   // B=1
    const int halfS = S / 2;
    const int grid  = S * CHUNKS;    // 2048 blocks

    const size_t tbl_bytes = (size_t)NIDX * EDIM * sizeof(float);

    if (ws_size >= tbl_bytes) {
        float* tbl = (float*)d_ws;
        build_table_kernel<<<(NIDX * EDIM + 255) / 256, 256, 0, stream>>>(W, bias, tbl);
        relpos2d_stream_kernel<<<grid, 256, 0, stream>>>(
            idxs, (const f32x4*)tbl, out, S, halfS);
    } else {
        relpos2d_lds_kernel<<<grid, 256, 0, stream>>>(idxs, W, bias, out, S, halfS);
    }
}

// Round 9
// 105.024 us; speedup vs baseline: 1.0155x; 1.0155x over previous
//
#include <hip/hip_runtime.h>

// RelativePositionalEncoding2D: out[b,i,j,e] = W[e, pos] + bias[e]
//   pos = clip(idxs[b,j] - idxs[b,i], -32, 32) + 32
// Shapes: B=1, S=1024, E=128, N=65. Output fp32 (1,S,S,E) = 512 MiB -> pure
// HBM-write-bound (floor ~80us at ~6.7 TB/s measured fill BW).
//
// R8 -> R9: revert to R6 base (best: 96.96us), redo the single-generation
// experiment WITHOUT R4's confounds. grid = 1024 blocks, one FULL i-row per
// block (512 KiB contiguous), prologue once per block (vs twice in R6's
// 2048-block mapping), one block generation (4/CU resident, exact).
// Coalesced prologue + plain stores + unroll 4 all preserved from R6.
// Single variable: block granularity / generation count.

#define MAXGAP 32
#define NIDX   65     // 2*MAXGAP+1
#define EDIM   128
#define E4     32     // EDIM/4 float4 per output row
#define PADE   132    // padded row stride in floats (528B, 16B-aligned)

typedef float f32x4 __attribute__((ext_vector_type(4)));

__global__ __launch_bounds__(256) void relpos2d_kernel(
    const int* __restrict__ idxs,
    const float* __restrict__ W,       // (E, N) row-major
    const float* __restrict__ bias,    // (E,)
    f32x4* __restrict__ out,           // (S*S, E4)
    int S)
{
    __shared__ float table[NIDX * PADE];  // 65*132*4 = 34,320 B
    __shared__ int   jidx[1024];          // full idxs row

    // table[p][e] = W[e*N + p] + bias[e]; read W coalesced, scatter to LDS.
    for (int t = threadIdx.x; t < NIDX * EDIM; t += 256) {
        float w = W[t];              // coalesced: t = e*NIDX + p
        int e = t / NIDX;            // magic-mul (constant divisor)
        int p = t - e * NIDX;
        table[p * PADE + e] = w + bias[e];
    }

    const int i = blockIdx.x;        // one full output row-block per block

    // stage idxs for the whole row (once per block)
    for (int t = threadIdx.x; t < S; t += 256)
        jidx[t] = idxs[t];

    __syncthreads();

    const int lane4 = threadIdx.x & 31;   // float4 slot within the 512B row
    const int jsub  = threadIdx.x >> 5;   // 0..7: j within this step
    const int idx_i = idxs[i];

    f32x4* __restrict__ orow = out + (size_t)i * S * E4;

    #pragma unroll 4
    for (int jj = 0; jj < S; jj += 8) {
        int j = jj + jsub;
        int d = jidx[j] - idx_i;                       // LDS broadcast read
        d = d < -MAXGAP ? -MAXGAP : (d > MAXGAP ? MAXGAP : d);
        int p = d + MAXGAP;

        f32x4 v = reinterpret_cast<const f32x4*>(&table[p * PADE])[lane4];
        orow[(size_t)j * E4 + lane4] = v;              // plain store
    }
}

extern "C" void kernel_launch(void* const* d_in, const int* in_sizes, int n_in,
                              void* d_out, int out_size, void* d_ws, size_t ws_size,
                              hipStream_t stream) {
    const int*   idxs = (const int*)  d_in[0];   // (B*S,) int32, B=1
    const float* W    = (const float*)d_in[1];   // (E, N) fp32
    const float* bias = (const float*)d_in[2];   // (E,)  fp32

    f32x4* out = (f32x4*)d_out;

    const int S    = in_sizes[0];   // B=1
    const int grid = S;             // 1024 blocks: one full i-row each, 4/CU

    relpos2d_kernel<<<grid, 256, 0, stream>>>(idxs, W, bias, out, S);
}

// Round 10
// 99.513 us; speedup vs baseline: 1.0717x; 1.0554x over previous
//
#include <hip/hip_runtime.h>

// RelativePositionalEncoding2D: out[b,i,j,e] = W[e, pos] + bias[e]
//   pos = clip(idxs[b,j] - idxs[b,i], -32, 32) + 32
// Shapes: B=1, S=1024, E=128, N=65. Output fp32 (1,S,S,E) = 512 MiB -> pure
// HBM-write-bound (floor ~80us at ~6.7 TB/s measured fill BW).
//
// R9 -> R10: granularity/density probe. Trend so far: 1024 blocks = 105us,
// 2048 blocks = 97us (fewer, wider-spread resident write streams = worse;
// theory: DRAM page/bank conflicts scale with active-window sparsity; the
// 1024 resident streams get denser as blocks shrink). This round: CHUNKS=4
// -> 4096 blocks, 128 KiB contiguous stores each, active write window
// ~128 MiB. Single variable vs R6 (best, 96.96us): CHUNKS 2->4.

#define MAXGAP 32
#define NIDX   65     // 2*MAXGAP+1
#define EDIM   128
#define E4     32     // EDIM/4 float4 per output row
#define PADE   132    // padded row stride in floats (528B, 16B-aligned)
#define CHUNKS 4      // quarter-rows per i

typedef float f32x4 __attribute__((ext_vector_type(4)));

__global__ __launch_bounds__(256) void relpos2d_kernel(
    const int* __restrict__ idxs,
    const float* __restrict__ W,       // (E, N) row-major
    const float* __restrict__ bias,    // (E,)
    f32x4* __restrict__ out,           // (S*S, E4)
    int S, int qS)
{
    __shared__ float table[NIDX * PADE];  // 65*132*4 = 34,320 B
    __shared__ int   jidx[256];           // qS entries (S=1024 -> 256)

    // table[p][e] = W[e*N + p] + bias[e]; read W coalesced, scatter to LDS.
    for (int t = threadIdx.x; t < NIDX * EDIM; t += 256) {
        float w = W[t];              // coalesced: t = e*NIDX + p
        int e = t / NIDX;            // magic-mul (constant divisor)
        int p = t - e * NIDX;
        table[p * PADE + e] = w + bias[e];
    }

    const int i     = blockIdx.x >> 2;       // CHUNKS == 4
    const int chunk = blockIdx.x & (CHUNKS - 1);
    const int jbase = chunk * qS;

    // stage this block's idxs[j] slice
    for (int t = threadIdx.x; t < qS; t += 256)
        jidx[t] = idxs[jbase + t];

    __syncthreads();

    const int lane4 = threadIdx.x & 31;   // float4 slot within the 512B row
    const int jsub  = threadIdx.x >> 5;   // 0..7: j within this step
    const int idx_i = idxs[i];

    f32x4* __restrict__ orow = out + (size_t)i * S * E4 + (size_t)jbase * E4;

    #pragma unroll 4
    for (int jj = 0; jj < qS; jj += 8) {
        int j = jj + jsub;
        int d = jidx[j] - idx_i;                       // LDS broadcast read
        d = d < -MAXGAP ? -MAXGAP : (d > MAXGAP ? MAXGAP : d);
        int p = d + MAXGAP;

        f32x4 v = reinterpret_cast<const f32x4*>(&table[p * PADE])[lane4];
        orow[(size_t)j * E4 + lane4] = v;              // plain store
    }
}

extern "C" void kernel_launch(void* const* d_in, const int* in_sizes, int n_in,
                              void* d_out, int out_size, void* d_ws, size_t ws_size,
                              hipStream_t stream) {
    const int*   idxs = (const int*)  d_in[0];   // (B*S,) int32, B=1
    const float* W    = (const float*)d_in[1];   // (E, N) fp32
    const float* bias = (const float*)d_in[2];   // (E,)  fp32

    f32x4* out = (f32x4*)d_out;

    const int S    = in_sizes[0];   // B=1
    const int qS   = S / CHUNKS;
    const int grid = S * CHUNKS;    // 4096 blocks: one (i, quarter-row) each

    relpos2d_kernel<<<grid, 256, 0, stream>>>(idxs, W, bias, out, S, qS);
}